// Round 1
// baseline (1288.755 us; speedup 1.0000x reference)
//
#include <hip/hip_runtime.h>
#include <hip/hip_bf16.h>

#define T_TOK 8192
#define D_DIM 1024
#define F_DIM 4096
#define NE 8

#define BM 128
#define BK 32

// 256x128 8-phase gateup geometry
#define BM2 256
#define BN2 128
#define BK2 64
#define KT2 (D_DIM / BK2)

typedef _Float16 v8h __attribute__((ext_vector_type(8)));
typedef float f32x4 __attribute__((ext_vector_type(4)));

__device__ __forceinline__ void async_lds16(void* lds, const void* g) {
    __builtin_amdgcn_global_load_lds(
        (const __attribute__((address_space(1))) void*)g,
        (__attribute__((address_space(3))) void*)lds,
        16, 0, 0);
}

// ---------------- router: logits -> top2 -> scatter ----------------
__global__ void router_kernel(const float* __restrict__ x,
                              const float* __restrict__ Wgate,
                              int* __restrict__ cnt,
                              int* __restrict__ rows,
                              float* __restrict__ wts) {
    int t = blockIdx.x;
    int lane = threadIdx.x;
    const float* xr = x + (size_t)t * D_DIM;
    float acc[NE];
#pragma unroll
    for (int e = 0; e < NE; ++e) acc[e] = 0.f;
#pragma unroll
    for (int i = 0; i < D_DIM / 64; ++i) {
        int d = i * 64 + lane;
        float xv = xr[d];
#pragma unroll
        for (int e = 0; e < NE; ++e) acc[e] += xv * Wgate[e * D_DIM + d];
    }
#pragma unroll
    for (int off = 32; off > 0; off >>= 1) {
#pragma unroll
        for (int e = 0; e < NE; ++e) acc[e] += __shfl_xor(acc[e], off, 64);
    }
    if (lane == 0) {
        int e0 = 0;
#pragma unroll
        for (int e = 1; e < NE; ++e) if (acc[e] > acc[e0]) e0 = e;
        int e1 = (e0 == 0) ? 1 : 0;
#pragma unroll
        for (int e = 0; e < NE; ++e) if (e != e0 && acc[e] > acc[e1]) e1 = e;
        float w0 = 1.f / (1.f + __expf(acc[e1] - acc[e0]));
        float w1 = 1.f - w0;
        int p0 = atomicAdd(&cnt[e0], 1);
        rows[e0 * T_TOK + p0] = 2 * t;
        wts[e0 * T_TOK + p0] = w0;
        int p1 = atomicAdd(&cnt[e1], 1);
        rows[e1 * T_TOK + p1] = 2 * t + 1;
        wts[e1 * T_TOK + p1] = w1;
    }
}

// ---------------- generic fp32 -> f16 convert (float4 granules) ----------------
__global__ void f32to16_kernel(const float* __restrict__ src, _Float16* __restrict__ dst) {
    int i = blockIdx.x * blockDim.x + threadIdx.x;
    float4 v = ((const float4*)src)[i];
    union { _Float16 h[4]; uint2 u; } pk;
    pk.h[0] = (_Float16)v.x; pk.h[1] = (_Float16)v.y;
    pk.h[2] = (_Float16)v.z; pk.h[3] = (_Float16)v.w;
    *(uint2*)&dst[(size_t)i * 4] = pk.u;
}

// ========== gateup: 256x128 tile, 8 waves, 4-phase/K-tile counted-vmcnt pipeline ==========
// A LDS = 256 token rows x 64 K; B LDS rows 0-127 = Wg cols [col0,col0+128),
// rows 128-255 = Wu cols (same range). Wave (wr,wc): M-frag i -> rows i*32+wr*16,
// cols (wc*2+j)*16. gate & up accumulated in the SAME lane -> in-register silu(g)*w*u.
// T2 XOR swizzle: 16B granule slot g holds logical granule g^(row&7); staged via
// pre-swizzled global source (linear LDS dest), read with same XOR.
// T3/T4: stage quarters of K-tile t+1 during t's 4 phases: p0:B-h0 p1:A-h0 p2:B-h1 p3:A-h1.
// vmcnt(4) (counted, never 0) at ends of p0, p1, p3. Raw s_barrier (no vmcnt0 drain).
__global__ __launch_bounds__(512, 2)
void gateup_kernel(const _Float16* __restrict__ Xh,
                   const _Float16* __restrict__ Wgh,
                   const _Float16* __restrict__ Wuh,
                   const int* __restrict__ cnt,
                   const int* __restrict__ rows,
                   const float* __restrict__ wts,
                   _Float16* __restrict__ H) {
    int e = blockIdx.z;
    int c = cnt[e];
    int row0 = blockIdx.y * BM2;
    if (row0 >= c) return;
    int col0 = blockIdx.x * BN2;

    __shared__ __align__(16) _Float16 Ab[2][BM2][BK2];   // 64 KB
    __shared__ __align__(16) _Float16 Bb[2][BM2][BK2];   // 64 KB
    __shared__ int hrow_s[BM2];
    __shared__ float w_s[BM2];

    int tid = threadIdx.x;
    int lane = tid & 63;
    int wv = tid >> 6;         // 0..7
    int wr = wv >> 2;          // 0..1
    int wc = wv & 3;           // 0..3

    if (tid < BM2) {
        int p = row0 + tid;
        if (p < c) { hrow_s[tid] = rows[e * T_TOK + p]; w_s[tid] = wts[e * T_TOK + p]; }
        else       { hrow_s[tid] = -1;                  w_s[tid] = 0.f; }
    }
    __syncthreads();

    // ---- staging geometry: chunk (wv,l) = 8 rows x 64 cols; lane -> row l8, slot granule g
    int l8 = lane >> 3;            // row within chunk = row&7
    int g  = lane & 7;             // physical 16B granule slot
    int lg = g ^ l8;               // logical granule (involution with row&7)

    int r0 = wv * 16 + l8;         // row-in-half, load0 (chunk wv*2)
    int r1 = r0 + 8;               // load1 (chunk wv*2+1)

    int hA00 = hrow_s[r0],       hA01 = hrow_s[r1];
    int hA10 = hrow_s[128 + r0], hA11 = hrow_s[128 + r1];
    const _Float16* sA00 = Xh + (size_t)(hA00 >= 0 ? (hA00 >> 1) : 0) * D_DIM + lg * 8;
    const _Float16* sA01 = Xh + (size_t)(hA01 >= 0 ? (hA01 >> 1) : 0) * D_DIM + lg * 8;
    const _Float16* sA10 = Xh + (size_t)(hA10 >= 0 ? (hA10 >> 1) : 0) * D_DIM + lg * 8;
    const _Float16* sA11 = Xh + (size_t)(hA11 >= 0 ? (hA11 >> 1) : 0) * D_DIM + lg * 8;
    const _Float16* sB00 = Wgh + ((size_t)e * F_DIM + col0 + r0) * D_DIM + lg * 8;
    const _Float16* sB01 = Wgh + ((size_t)e * F_DIM + col0 + r1) * D_DIM + lg * 8;
    const _Float16* sB10 = Wuh + ((size_t)e * F_DIM + col0 + r0) * D_DIM + lg * 8;
    const _Float16* sB11 = Wuh + ((size_t)e * F_DIM + col0 + r1) * D_DIM + lg * 8;

    int stO0 = wv * 2048 + lane * 16;   // byte offset of (chunk wv*2, lane) within a half

    // ---- fragment-read constants (swizzled)
    int m16 = lane & 15, q4 = lane >> 4;
    int rx = m16 & 7;
    int cb0 = ((q4 ^ rx) << 4);          // kk=0: logical granule q4
    int cb1 = (((4 + q4) ^ rx) << 4);    // kk=1: logical granule 4+q4
    const char* arB = (const char*)Ab + (wr * 16 + m16) * 128;
    const char* brB = (const char*)Bb + m16 * 128 + wc * 4096;

    // ---- prologue: stage full tile 0 into buffer 0 (order: Bh0, Ah0, Bh1, Ah1)
    {
        char* a0 = (char*)Ab + stO0;
        char* b0 = (char*)Bb + stO0;
        async_lds16(b0,                sB00);
        async_lds16(b0 + 1024,         sB01);
        async_lds16(a0,                sA00);
        async_lds16(a0 + 1024,         sA01);
        async_lds16(b0 + 16384,        sB10);
        async_lds16(b0 + 16384 + 1024, sB11);
        async_lds16(a0 + 16384,        sA10);
        async_lds16(a0 + 16384 + 1024, sA11);
        asm volatile("s_waitcnt vmcnt(4)" ::: "memory");  // Bh0,Ah0 landed
        __builtin_amdgcn_s_barrier();
    }

    f32x4 accg[8][2], accu[8][2];
#pragma unroll
    for (int i = 0; i < 8; ++i)
#pragma unroll
        for (int j = 0; j < 2; ++j) { accg[i][j] = (f32x4)0.f; accu[i][j] = (f32x4)0.f; }

    int cur = 0;
#pragma unroll 1
    for (int t = 0; t < KT2; ++t) {
        int kn = (t + 1 < KT2) ? (t + 1) * BK2 : 0;   // clamped next-tile K offset
        int nb = cur ^ 1;
        const char* ar = arB + cur * 32768;
        const char* br = brB + cur * 32768;
        char* aD = (char*)Ab + nb * 32768 + stO0;
        char* bD = (char*)Bb + nb * 32768 + stO0;

        v8h af[4][2], bg[2][2], bu[2][2];

        // ---------- phase 0: gate, M-frags 0-3 (A-h0, B-h0) ----------
#pragma unroll
        for (int i = 0; i < 4; ++i) {
            af[i][0] = *(const v8h*)(ar + i * 4096 + cb0);
            af[i][1] = *(const v8h*)(ar + i * 4096 + cb1);
        }
#pragma unroll
        for (int j = 0; j < 2; ++j) {
            bg[j][0] = *(const v8h*)(br + j * 2048 + cb0);
            bg[j][1] = *(const v8h*)(br + j * 2048 + cb1);
        }
        async_lds16(bD,        sB00 + kn);
        async_lds16(bD + 1024, sB01 + kn);
        __builtin_amdgcn_s_barrier();
        __builtin_amdgcn_s_setprio(1);
#pragma unroll
        for (int i = 0; i < 4; ++i)
#pragma unroll
            for (int j = 0; j < 2; ++j) {
                accg[i][j] = __builtin_amdgcn_mfma_f32_16x16x32_f16(af[i][0], bg[j][0], accg[i][j], 0, 0, 0);
                accg[i][j] = __builtin_amdgcn_mfma_f32_16x16x32_f16(af[i][1], bg[j][1], accg[i][j], 0, 0, 0);
            }
        __builtin_amdgcn_s_setprio(0);
        asm volatile("s_waitcnt vmcnt(4)" ::: "memory");  // next-tile Bh1 ready before p1
        __builtin_amdgcn_s_barrier();

        // ---------- phase 1: up, M-frags 0-3 (B-h1; af reused) ----------
#pragma unroll
        for (int j = 0; j < 2; ++j) {
            bu[j][0] = *(const v8h*)(br + 16384 + j * 2048 + cb0);
            bu[j][1] = *(const v8h*)(br + 16384 + j * 2048 + cb1);
        }
        async_lds16(aD,        sA00 + kn);
        async_lds16(aD + 1024, sA01 + kn);
        __builtin_amdgcn_s_barrier();
        __builtin_amdgcn_s_setprio(1);
#pragma unroll
        for (int i = 0; i < 4; ++i)
#pragma unroll
            for (int j = 0; j < 2; ++j) {
                accu[i][j] = __builtin_amdgcn_mfma_f32_16x16x32_f16(af[i][0], bu[j][0], accu[i][j], 0, 0, 0);
                accu[i][j] = __builtin_amdgcn_mfma_f32_16x16x32_f16(af[i][1], bu[j][1], accu[i][j], 0, 0, 0);
            }
        __builtin_amdgcn_s_setprio(0);
        asm volatile("s_waitcnt vmcnt(4)" ::: "memory");  // next-tile Ah1 ready before p2
        __builtin_amdgcn_s_barrier();

        // ---------- phase 2: gate, M-frags 4-7 (A-h1; bg reused) ----------
#pragma unroll
        for (int i = 0; i < 4; ++i) {
            af[i][0] = *(const v8h*)(ar + (i + 4) * 4096 + cb0);
            af[i][1] = *(const v8h*)(ar + (i + 4) * 4096 + cb1);
        }
        async_lds16(bD + 16384,        sB10 + kn);
        async_lds16(bD + 16384 + 1024, sB11 + kn);
        __builtin_amdgcn_s_barrier();
        __builtin_amdgcn_s_setprio(1);
#pragma unroll
        for (int i = 0; i < 4; ++i)
#pragma unroll
            for (int j = 0; j < 2; ++j) {
                accg[i + 4][j] = __builtin_amdgcn_mfma_f32_16x16x32_f16(af[i][0], bg[j][0], accg[i + 4][j], 0, 0, 0);
                accg[i + 4][j] = __builtin_amdgcn_mfma_f32_16x16x32_f16(af[i][1], bg[j][1], accg[i + 4][j], 0, 0, 0);
            }
        __builtin_amdgcn_s_setprio(0);
        __builtin_amdgcn_s_barrier();

        // ---------- phase 3: up, M-frags 4-7 (af + bu reused) ----------
        async_lds16(aD + 16384,        sA10 + kn);
        async_lds16(aD + 16384 + 1024, sA11 + kn);
        __builtin_amdgcn_s_barrier();
        __builtin_amdgcn_s_setprio(1);
#pragma unroll
        for (int i = 0; i < 4; ++i)
#pragma unroll
            for (int j = 0; j < 2; ++j) {
                accu[i + 4][j] = __builtin_amdgcn_mfma_f32_16x16x32_f16(af[i][0], bu[j][0], accu[i + 4][j], 0, 0, 0);
                accu[i + 4][j] = __builtin_amdgcn_mfma_f32_16x16x32_f16(af[i][1], bu[j][1], accu[i + 4][j], 0, 0, 0);
            }
        __builtin_amdgcn_s_setprio(0);
        asm volatile("s_waitcnt vmcnt(4)" ::: "memory");  // next-tile Bh0,Ah0 ready before t+1.p0
        __builtin_amdgcn_s_barrier();

        cur = nb;
    }

    // ---------- epilogue: h = silu(g) * w * u -> H (f16) ----------
    int cl = lane & 15;
#pragma unroll
    for (int i = 0; i < 8; ++i) {
#pragma unroll
        for (int j = 0; j < 2; ++j) {
            f32x4 gv = accg[i][j];
            f32x4 uv = accu[i][j];
#pragma unroll
            for (int r4 = 0; r4 < 4; ++r4) {
                int r = i * 32 + wr * 16 + q4 * 4 + r4;
                int hr = hrow_s[r];
                if (hr < 0) continue;
                float gg = gv[r4];
                float h = gg / (1.f + __expf(-gg)) * w_s[r] * uv[r4];
                H[(size_t)hr * F_DIM + col0 + (wc * 2 + j) * 16 + cl] = (_Float16)h;
            }
        }
    }
}

// ---------------- down GEMM: H @ Wd^T -> O (fp32, slot-indexed) ----------------
__global__ __launch_bounds__(256, 2)
void down_kernel(const _Float16* __restrict__ H,
                 const _Float16* __restrict__ Wdh,
                 const int* __restrict__ cnt,
                 const int* __restrict__ rows,
                 float* __restrict__ O) {
    int e = blockIdx.z;
    int c = cnt[e];
    int row0 = blockIdx.y * BM;
    if (row0 >= c) return;
    int col0 = blockIdx.x * 128;

    __shared__ __align__(16) _Float16 As[BM][BK];
    __shared__ __align__(16) _Float16 Bs[128][BK];
    __shared__ int hrow_s[BM];

    int tid = threadIdx.x;
    int lane = tid & 63;
    int wave = tid >> 6;
    int wr = wave >> 1, wc = wave & 1;

    if (tid < BM) {
        int p = row0 + tid;
        hrow_s[tid] = (p < c) ? rows[e * T_TOK + p] : -1;
    }
    __syncthreads();

    int srow = tid >> 2;
    int kch = tid & 3;
    int hr0 = hrow_s[srow], hr1 = hrow_s[srow + 64];
    int r0 = (hr0 >= 0) ? hr0 : 0;
    int r1 = (hr1 >= 0) ? hr1 : 0;

    const _Float16* a0 = H + (size_t)r0 * F_DIM + kch * 8;
    const _Float16* a1 = H + (size_t)r1 * F_DIM + kch * 8;
    const _Float16* b0 = Wdh + ((size_t)e * D_DIM + col0 + srow) * F_DIM + kch * 8;
    const _Float16* b1 = b0 + (size_t)64 * F_DIM;

    _Float16* lA0 = &As[srow][kch * 8];
    _Float16* lA1 = &As[srow + 64][kch * 8];
    _Float16* lB0 = &Bs[srow][kch * 8];
    _Float16* lB1 = &Bs[srow + 64][kch * 8];

    f32x4 acc[4][4];
#pragma unroll
    for (int i = 0; i < 4; ++i)
#pragma unroll
        for (int j = 0; j < 4; ++j) acc[i][j] = (f32x4)0.f;

    int m16 = lane & 15, q8 = (lane >> 4) * 8;

    for (int k0 = 0; k0 < F_DIM; k0 += BK) {
        async_lds16(lA0, a0 + k0);
        async_lds16(lA1, a1 + k0);
        async_lds16(lB0, b0 + k0);
        async_lds16(lB1, b1 + k0);
        __syncthreads();

        v8h af[4], bf[4];
#pragma unroll
        for (int i = 0; i < 4; ++i)
            af[i] = *(const v8h*)&As[wr * 64 + i * 16 + m16][q8];
#pragma unroll
        for (int j = 0; j < 4; ++j)
            bf[j] = *(const v8h*)&Bs[wc * 64 + j * 16 + m16][q8];
#pragma unroll
        for (int i = 0; i < 4; ++i)
#pragma unroll
            for (int j = 0; j < 4; ++j)
                acc[i][j] = __builtin_amdgcn_mfma_f32_16x16x32_f16(af[i], bf[j], acc[i][j], 0, 0, 0);
        __syncthreads();
    }

    int q = lane >> 4, cl = lane & 15;
#pragma unroll
    for (int i = 0; i < 4; ++i) {
#pragma unroll
        for (int r4 = 0; r4 < 4; ++r4) {
            int r = wr * 64 + i * 16 + q * 4 + r4;
            int hr = hrow_s[r];
            if (hr < 0) continue;
#pragma unroll
            for (int j = 0; j < 4; ++j) {
                int col = col0 + wc * 64 + j * 16 + cl;
                O[(size_t)hr * D_DIM + col] = acc[i][j][r4];
            }
        }
    }
}

// ---------------- combine: out[t] = O[2t] + O[2t+1] ----------------
__global__ void combine_kernel(const float* __restrict__ O, float* __restrict__ out) {
    int t = blockIdx.x;
    int d = threadIdx.x;
    const float4* a = (const float4*)(O + (size_t)(2 * t) * D_DIM);
    const float4* b = (const float4*)(O + (size_t)(2 * t + 1) * D_DIM);
    float4 va = a[d], vb = b[d];
    float4 r; r.x = va.x + vb.x; r.y = va.y + vb.y; r.z = va.z + vb.z; r.w = va.w + vb.w;
    ((float4*)(out + (size_t)t * D_DIM))[d] = r;
}

extern "C" void kernel_launch(void* const* d_in, const int* in_sizes, int n_in,
                              void* d_out, int out_size, void* d_ws, size_t ws_size,
                              hipStream_t stream) {
    const float* x     = (const float*)d_in[0];
    const float* Wgate = (const float*)d_in[1];
    const float* Wg    = (const float*)d_in[2];
    const float* Wu    = (const float*)d_in[3];
    const float* Wd    = (const float*)d_in[4];
    float* out = (float*)d_out;

    char* w = (char*)d_ws;
    int*      cnt  = (int*)w;                          // 32 B, zeroed below
    int*      rows = (int*)(w + 1024);                 // 256 KB
    float*    wts  = (float*)(w + 263168);             // 256 KB
    _Float16* Xh   = (_Float16*)(w + 525312);          // 16 MB

    const size_t OFF_WGH = 17302528;                   // 64 MB f16
    const size_t OFF_WUH = 84411392;
    const size_t OFF_WDH = 151520256;
    const size_t OFF_H   = 218629120;                  // 128 MB
    const size_t OFF_O   = 352846848;                  // 64 MB

    _Float16* Wgh = (_Float16*)(w + OFF_WGH);
    _Float16* Wuh = (_Float16*)(w + OFF_WUH);
    _Float16* Wdh = (_Float16*)(w + OFF_WDH);
    _Float16* H   = (_Float16*)(w + OFF_H);
    float*    O   = (float*)(w + OFF_O);

    hipMemsetAsync(w, 0, 1024, stream);  // zero expert counters

    router_kernel<<<T_TOK, 64, 0, stream>>>(x, Wgate, cnt, rows, wts);
    f32to16_kernel<<<(T_TOK * D_DIM / 4) / 256, 256, 0, stream>>>(x, Xh);

    const int WN4 = (NE * F_DIM * D_DIM / 4);
    f32to16_kernel<<<WN4 / 256, 256, 0, stream>>>(Wg, Wgh);
    f32to16_kernel<<<WN4 / 256, 256, 0, stream>>>(Wu, Wuh);
    f32to16_kernel<<<WN4 / 256, 256, 0, stream>>>(Wd, Wdh);

    gateup_kernel<<<dim3(F_DIM / BN2, T_TOK / BM2, NE), 512, 0, stream>>>(
        Xh, Wgh, Wuh, cnt, rows, wts, H);
    down_kernel<<<dim3(D_DIM / 128, T_TOK / BM, NE), 256, 0, stream>>>(
        H, Wdh, cnt, rows, O);
    combine_kernel<<<T_TOK, 256, 0, stream>>>(O, out);
}

// Round 2
// 1188.130 us; speedup vs baseline: 1.0847x; 1.0847x over previous
//
#include <hip/hip_runtime.h>
#include <hip/hip_bf16.h>

#define T_TOK 8192
#define D_DIM 1024
#define F_DIM 4096
#define NE 8

#define BM 128
#define BK 32

// 256x128 8-phase gateup geometry
#define BM2 256
#define BN2 128
#define BK2 64
#define KT2 (D_DIM / BK2)

typedef _Float16 v8h __attribute__((ext_vector_type(8)));
typedef float f32x4 __attribute__((ext_vector_type(4)));

__device__ __forceinline__ void async_lds16(void* lds, const void* g) {
    __builtin_amdgcn_global_load_lds(
        (const __attribute__((address_space(1))) void*)g,
        (__attribute__((address_space(3))) void*)lds,
        16, 0, 0);
}

// opaque LDS read: no alias info -> compiler cannot insert vmcnt drains for it.
// Caller MUST s_waitcnt lgkmcnt(0) + sched_barrier(0) before consuming.
__device__ __forceinline__ v8h ds_read128(const void* p) {
    v8h r;
    unsigned a = (unsigned)(size_t)(const __attribute__((address_space(3))) void*)p;
    asm volatile("ds_read_b128 %0, %1" : "=v"(r) : "v"(a));
    return r;
}

// ---------------- router: logits -> top2 -> scatter ----------------
__global__ void router_kernel(const float* __restrict__ x,
                              const float* __restrict__ Wgate,
                              int* __restrict__ cnt,
                              int* __restrict__ rows,
                              float* __restrict__ wts) {
    int t = blockIdx.x;
    int lane = threadIdx.x;
    const float* xr = x + (size_t)t * D_DIM;
    float acc[NE];
#pragma unroll
    for (int e = 0; e < NE; ++e) acc[e] = 0.f;
#pragma unroll
    for (int i = 0; i < D_DIM / 64; ++i) {
        int d = i * 64 + lane;
        float xv = xr[d];
#pragma unroll
        for (int e = 0; e < NE; ++e) acc[e] += xv * Wgate[e * D_DIM + d];
    }
#pragma unroll
    for (int off = 32; off > 0; off >>= 1) {
#pragma unroll
        for (int e = 0; e < NE; ++e) acc[e] += __shfl_xor(acc[e], off, 64);
    }
    if (lane == 0) {
        int e0 = 0;
#pragma unroll
        for (int e = 1; e < NE; ++e) if (acc[e] > acc[e0]) e0 = e;
        int e1 = (e0 == 0) ? 1 : 0;
#pragma unroll
        for (int e = 0; e < NE; ++e) if (e != e0 && acc[e] > acc[e1]) e1 = e;
        float w0 = 1.f / (1.f + __expf(acc[e1] - acc[e0]));
        float w1 = 1.f - w0;
        int p0 = atomicAdd(&cnt[e0], 1);
        rows[e0 * T_TOK + p0] = 2 * t;
        wts[e0 * T_TOK + p0] = w0;
        int p1 = atomicAdd(&cnt[e1], 1);
        rows[e1 * T_TOK + p1] = 2 * t + 1;
        wts[e1 * T_TOK + p1] = w1;
    }
}

// ---------------- generic fp32 -> f16 convert (float4 granules) ----------------
__global__ void f32to16_kernel(const float* __restrict__ src, _Float16* __restrict__ dst) {
    int i = blockIdx.x * blockDim.x + threadIdx.x;
    float4 v = ((const float4*)src)[i];
    union { _Float16 h[4]; uint2 u; } pk;
    pk.h[0] = (_Float16)v.x; pk.h[1] = (_Float16)v.y;
    pk.h[2] = (_Float16)v.z; pk.h[3] = (_Float16)v.w;
    *(uint2*)&dst[(size_t)i * 4] = pk.u;
}

// ========== gateup: 256x128 tile, 8 waves, 4-phase/K-tile counted-vmcnt pipeline ==========
// Same schedule as r1; ONLY change: fragment LDS reads are inline-asm ds_read_b128
// (opaque to alias analysis) + explicit "barrier; lgkmcnt(0); sched_barrier(0)" before
// each MFMA cluster. This removes compiler-inserted vmcnt(0) drains that defeated the
// counted-vmcnt pipeline in r1 (MfmaUtil 29%).
__global__ __launch_bounds__(512, 2)
void gateup_kernel(const _Float16* __restrict__ Xh,
                   const _Float16* __restrict__ Wgh,
                   const _Float16* __restrict__ Wuh,
                   const int* __restrict__ cnt,
                   const int* __restrict__ rows,
                   const float* __restrict__ wts,
                   _Float16* __restrict__ H) {
    int e = blockIdx.z;
    int c = cnt[e];
    int row0 = blockIdx.y * BM2;
    if (row0 >= c) return;
    int col0 = blockIdx.x * BN2;

    __shared__ __align__(16) _Float16 Ab[2][BM2][BK2];   // 64 KB
    __shared__ __align__(16) _Float16 Bb[2][BM2][BK2];   // 64 KB
    __shared__ int hrow_s[BM2];
    __shared__ float w_s[BM2];

    int tid = threadIdx.x;
    int lane = tid & 63;
    int wv = tid >> 6;         // 0..7
    int wr = wv >> 2;          // 0..1
    int wc = wv & 3;           // 0..3

    if (tid < BM2) {
        int p = row0 + tid;
        if (p < c) { hrow_s[tid] = rows[e * T_TOK + p]; w_s[tid] = wts[e * T_TOK + p]; }
        else       { hrow_s[tid] = -1;                  w_s[tid] = 0.f; }
    }
    __syncthreads();

    // ---- staging geometry: chunk (wv,l) = 8 rows x 64 cols; lane -> row l8, slot granule g
    int l8 = lane >> 3;            // row within chunk = row&7
    int g  = lane & 7;             // physical 16B granule slot
    int lg = g ^ l8;               // logical granule (involution with row&7)

    int r0 = wv * 16 + l8;         // row-in-half, load0 (chunk wv*2)
    int r1 = r0 + 8;               // load1 (chunk wv*2+1)

    int hA00 = hrow_s[r0],       hA01 = hrow_s[r1];
    int hA10 = hrow_s[128 + r0], hA11 = hrow_s[128 + r1];
    const _Float16* sA00 = Xh + (size_t)(hA00 >= 0 ? (hA00 >> 1) : 0) * D_DIM + lg * 8;
    const _Float16* sA01 = Xh + (size_t)(hA01 >= 0 ? (hA01 >> 1) : 0) * D_DIM + lg * 8;
    const _Float16* sA10 = Xh + (size_t)(hA10 >= 0 ? (hA10 >> 1) : 0) * D_DIM + lg * 8;
    const _Float16* sA11 = Xh + (size_t)(hA11 >= 0 ? (hA11 >> 1) : 0) * D_DIM + lg * 8;
    const _Float16* sB00 = Wgh + ((size_t)e * F_DIM + col0 + r0) * D_DIM + lg * 8;
    const _Float16* sB01 = Wgh + ((size_t)e * F_DIM + col0 + r1) * D_DIM + lg * 8;
    const _Float16* sB10 = Wuh + ((size_t)e * F_DIM + col0 + r0) * D_DIM + lg * 8;
    const _Float16* sB11 = Wuh + ((size_t)e * F_DIM + col0 + r1) * D_DIM + lg * 8;

    int stO0 = wv * 2048 + lane * 16;   // byte offset of (chunk wv*2, lane) within a half

    // ---- fragment-read constants (swizzled)
    int m16 = lane & 15, q4 = lane >> 4;
    int rx = m16 & 7;
    int cb0 = ((q4 ^ rx) << 4);          // kk=0: logical granule q4
    int cb1 = (((4 + q4) ^ rx) << 4);    // kk=1: logical granule 4+q4
    const char* arB = (const char*)Ab + (wr * 16 + m16) * 128;
    const char* brB = (const char*)Bb + m16 * 128 + wc * 4096;

    // ---- prologue: stage full tile 0 into buffer 0 (order: Bh0, Ah0, Bh1, Ah1)
    {
        char* a0 = (char*)Ab + stO0;
        char* b0 = (char*)Bb + stO0;
        async_lds16(b0,                sB00);
        async_lds16(b0 + 1024,         sB01);
        async_lds16(a0,                sA00);
        async_lds16(a0 + 1024,         sA01);
        async_lds16(b0 + 16384,        sB10);
        async_lds16(b0 + 16384 + 1024, sB11);
        async_lds16(a0 + 16384,        sA10);
        async_lds16(a0 + 16384 + 1024, sA11);
        asm volatile("s_waitcnt vmcnt(4)" ::: "memory");  // Bh0,Ah0 landed
        __builtin_amdgcn_s_barrier();
    }

    f32x4 accg[8][2], accu[8][2];
#pragma unroll
    for (int i = 0; i < 8; ++i)
#pragma unroll
        for (int j = 0; j < 2; ++j) { accg[i][j] = (f32x4)0.f; accu[i][j] = (f32x4)0.f; }

    int cur = 0;
#pragma unroll 1
    for (int t = 0; t < KT2; ++t) {
        int kn = (t + 1 < KT2) ? (t + 1) * BK2 : 0;   // clamped next-tile K offset
        int nb = cur ^ 1;
        const char* ar = arB + cur * 32768;
        const char* br = brB + cur * 32768;
        char* aD = (char*)Ab + nb * 32768 + stO0;
        char* bD = (char*)Bb + nb * 32768 + stO0;

        v8h af[4][2], bg[2][2], bu[2][2];

        // ---------- phase 0: gate, M-frags 0-3 (A-h0, B-h0) ----------
#pragma unroll
        for (int i = 0; i < 4; ++i) {
            af[i][0] = ds_read128(ar + i * 4096 + cb0);
            af[i][1] = ds_read128(ar + i * 4096 + cb1);
        }
#pragma unroll
        for (int j = 0; j < 2; ++j) {
            bg[j][0] = ds_read128(br + j * 2048 + cb0);
            bg[j][1] = ds_read128(br + j * 2048 + cb1);
        }
        async_lds16(bD,        sB00 + kn);
        async_lds16(bD + 1024, sB01 + kn);
        __builtin_amdgcn_s_barrier();
        asm volatile("s_waitcnt lgkmcnt(0)" ::: "memory");
        __builtin_amdgcn_sched_barrier(0);
        __builtin_amdgcn_s_setprio(1);
#pragma unroll
        for (int i = 0; i < 4; ++i)
#pragma unroll
            for (int j = 0; j < 2; ++j) {
                accg[i][j] = __builtin_amdgcn_mfma_f32_16x16x32_f16(af[i][0], bg[j][0], accg[i][j], 0, 0, 0);
                accg[i][j] = __builtin_amdgcn_mfma_f32_16x16x32_f16(af[i][1], bg[j][1], accg[i][j], 0, 0, 0);
            }
        __builtin_amdgcn_s_setprio(0);
        asm volatile("s_waitcnt vmcnt(4)" ::: "memory");  // next-tile Bh1 ready before p1
        __builtin_amdgcn_s_barrier();

        // ---------- phase 1: up, M-frags 0-3 (B-h1; af reused) ----------
#pragma unroll
        for (int j = 0; j < 2; ++j) {
            bu[j][0] = ds_read128(br + 16384 + j * 2048 + cb0);
            bu[j][1] = ds_read128(br + 16384 + j * 2048 + cb1);
        }
        async_lds16(aD,        sA00 + kn);
        async_lds16(aD + 1024, sA01 + kn);
        __builtin_amdgcn_s_barrier();
        asm volatile("s_waitcnt lgkmcnt(0)" ::: "memory");
        __builtin_amdgcn_sched_barrier(0);
        __builtin_amdgcn_s_setprio(1);
#pragma unroll
        for (int i = 0; i < 4; ++i)
#pragma unroll
            for (int j = 0; j < 2; ++j) {
                accu[i][j] = __builtin_amdgcn_mfma_f32_16x16x32_f16(af[i][0], bu[j][0], accu[i][j], 0, 0, 0);
                accu[i][j] = __builtin_amdgcn_mfma_f32_16x16x32_f16(af[i][1], bu[j][1], accu[i][j], 0, 0, 0);
            }
        __builtin_amdgcn_s_setprio(0);
        asm volatile("s_waitcnt vmcnt(4)" ::: "memory");  // next-tile Ah1 ready before p2
        __builtin_amdgcn_s_barrier();

        // ---------- phase 2: gate, M-frags 4-7 (A-h1; bg reused) ----------
#pragma unroll
        for (int i = 0; i < 4; ++i) {
            af[i][0] = ds_read128(ar + (i + 4) * 4096 + cb0);
            af[i][1] = ds_read128(ar + (i + 4) * 4096 + cb1);
        }
        async_lds16(bD + 16384,        sB10 + kn);
        async_lds16(bD + 16384 + 1024, sB11 + kn);
        __builtin_amdgcn_s_barrier();
        asm volatile("s_waitcnt lgkmcnt(0)" ::: "memory");
        __builtin_amdgcn_sched_barrier(0);
        __builtin_amdgcn_s_setprio(1);
#pragma unroll
        for (int i = 0; i < 4; ++i)
#pragma unroll
            for (int j = 0; j < 2; ++j) {
                accg[i + 4][j] = __builtin_amdgcn_mfma_f32_16x16x32_f16(af[i][0], bg[j][0], accg[i + 4][j], 0, 0, 0);
                accg[i + 4][j] = __builtin_amdgcn_mfma_f32_16x16x32_f16(af[i][1], bg[j][1], accg[i + 4][j], 0, 0, 0);
            }
        __builtin_amdgcn_s_setprio(0);
        __builtin_amdgcn_s_barrier();

        // ---------- phase 3: up, M-frags 4-7 (af + bu reused) ----------
        async_lds16(aD + 16384,        sA10 + kn);
        async_lds16(aD + 16384 + 1024, sA11 + kn);
        __builtin_amdgcn_s_barrier();
        __builtin_amdgcn_s_setprio(1);
#pragma unroll
        for (int i = 0; i < 4; ++i)
#pragma unroll
            for (int j = 0; j < 2; ++j) {
                accu[i + 4][j] = __builtin_amdgcn_mfma_f32_16x16x32_f16(af[i][0], bu[j][0], accu[i + 4][j], 0, 0, 0);
                accu[i + 4][j] = __builtin_amdgcn_mfma_f32_16x16x32_f16(af[i][1], bu[j][1], accu[i + 4][j], 0, 0, 0);
            }
        __builtin_amdgcn_s_setprio(0);
        asm volatile("s_waitcnt vmcnt(4)" ::: "memory");  // next-tile Bh0,Ah0 ready before t+1.p0
        __builtin_amdgcn_s_barrier();

        cur = nb;
    }

    // ---------- epilogue: h = silu(g) * w * u -> H (f16) ----------
    int cl = lane & 15;
#pragma unroll
    for (int i = 0; i < 8; ++i) {
#pragma unroll
        for (int j = 0; j < 2; ++j) {
            f32x4 gv = accg[i][j];
            f32x4 uv = accu[i][j];
#pragma unroll
            for (int r4 = 0; r4 < 4; ++r4) {
                int r = i * 32 + wr * 16 + q4 * 4 + r4;
                int hr = hrow_s[r];
                if (hr < 0) continue;
                float gg = gv[r4];
                float h = gg / (1.f + __expf(-gg)) * w_s[r] * uv[r4];
                H[(size_t)hr * F_DIM + col0 + (wc * 2 + j) * 16 + cl] = (_Float16)h;
            }
        }
    }
}

// ---------------- down GEMM: H @ Wd^T -> O (fp32, slot-indexed) ----------------
__global__ __launch_bounds__(256, 2)
void down_kernel(const _Float16* __restrict__ H,
                 const _Float16* __restrict__ Wdh,
                 const int* __restrict__ cnt,
                 const int* __restrict__ rows,
                 float* __restrict__ O) {
    int e = blockIdx.z;
    int c = cnt[e];
    int row0 = blockIdx.y * BM;
    if (row0 >= c) return;
    int col0 = blockIdx.x * 128;

    __shared__ __align__(16) _Float16 As[BM][BK];
    __shared__ __align__(16) _Float16 Bs[128][BK];
    __shared__ int hrow_s[BM];

    int tid = threadIdx.x;
    int lane = tid & 63;
    int wave = tid >> 6;
    int wr = wave >> 1, wc = wave & 1;

    if (tid < BM) {
        int p = row0 + tid;
        hrow_s[tid] = (p < c) ? rows[e * T_TOK + p] : -1;
    }
    __syncthreads();

    int srow = tid >> 2;
    int kch = tid & 3;
    int hr0 = hrow_s[srow], hr1 = hrow_s[srow + 64];
    int r0 = (hr0 >= 0) ? hr0 : 0;
    int r1 = (hr1 >= 0) ? hr1 : 0;

    const _Float16* a0 = H + (size_t)r0 * F_DIM + kch * 8;
    const _Float16* a1 = H + (size_t)r1 * F_DIM + kch * 8;
    const _Float16* b0 = Wdh + ((size_t)e * D_DIM + col0 + srow) * F_DIM + kch * 8;
    const _Float16* b1 = b0 + (size_t)64 * F_DIM;

    _Float16* lA0 = &As[srow][kch * 8];
    _Float16* lA1 = &As[srow + 64][kch * 8];
    _Float16* lB0 = &Bs[srow][kch * 8];
    _Float16* lB1 = &Bs[srow + 64][kch * 8];

    f32x4 acc[4][4];
#pragma unroll
    for (int i = 0; i < 4; ++i)
#pragma unroll
        for (int j = 0; j < 4; ++j) acc[i][j] = (f32x4)0.f;

    int m16 = lane & 15, q8 = (lane >> 4) * 8;

    for (int k0 = 0; k0 < F_DIM; k0 += BK) {
        async_lds16(lA0, a0 + k0);
        async_lds16(lA1, a1 + k0);
        async_lds16(lB0, b0 + k0);
        async_lds16(lB1, b1 + k0);
        __syncthreads();

        v8h af[4], bf[4];
#pragma unroll
        for (int i = 0; i < 4; ++i)
            af[i] = *(const v8h*)&As[wr * 64 + i * 16 + m16][q8];
#pragma unroll
        for (int j = 0; j < 4; ++j)
            bf[j] = *(const v8h*)&Bs[wc * 64 + j * 16 + m16][q8];
#pragma unroll
        for (int i = 0; i < 4; ++i)
#pragma unroll
            for (int j = 0; j < 4; ++j)
                acc[i][j] = __builtin_amdgcn_mfma_f32_16x16x32_f16(af[i], bf[j], acc[i][j], 0, 0, 0);
        __syncthreads();
    }

    int q = lane >> 4, cl = lane & 15;
#pragma unroll
    for (int i = 0; i < 4; ++i) {
#pragma unroll
        for (int r4 = 0; r4 < 4; ++r4) {
            int r = wr * 64 + i * 16 + q * 4 + r4;
            int hr = hrow_s[r];
            if (hr < 0) continue;
#pragma unroll
            for (int j = 0; j < 4; ++j) {
                int col = col0 + wc * 64 + j * 16 + cl;
                O[(size_t)hr * D_DIM + col] = acc[i][j][r4];
            }
        }
    }
}

// ---------------- combine: out[t] = O[2t] + O[2t+1] ----------------
__global__ void combine_kernel(const float* __restrict__ O, float* __restrict__ out) {
    int t = blockIdx.x;
    int d = threadIdx.x;
    const float4* a = (const float4*)(O + (size_t)(2 * t) * D_DIM);
    const float4* b = (const float4*)(O + (size_t)(2 * t + 1) * D_DIM);
    float4 va = a[d], vb = b[d];
    float4 r; r.x = va.x + vb.x; r.y = va.y + vb.y; r.z = va.z + vb.z; r.w = va.w + vb.w;
    ((float4*)(out + (size_t)t * D_DIM))[d] = r;
}

extern "C" void kernel_launch(void* const* d_in, const int* in_sizes, int n_in,
                              void* d_out, int out_size, void* d_ws, size_t ws_size,
                              hipStream_t stream) {
    const float* x     = (const float*)d_in[0];
    const float* Wgate = (const float*)d_in[1];
    const float* Wg    = (const float*)d_in[2];
    const float* Wu    = (const float*)d_in[3];
    const float* Wd    = (const float*)d_in[4];
    float* out = (float*)d_out;

    char* w = (char*)d_ws;
    int*      cnt  = (int*)w;                          // 32 B, zeroed below
    int*      rows = (int*)(w + 1024);                 // 256 KB
    float*    wts  = (float*)(w + 263168);             // 256 KB
    _Float16* Xh   = (_Float16*)(w + 525312);          // 16 MB

    const size_t OFF_WGH = 17302528;                   // 64 MB f16
    const size_t OFF_WUH = 84411392;
    const size_t OFF_WDH = 151520256;
    const size_t OFF_H   = 218629120;                  // 128 MB
    const size_t OFF_O   = 352846848;                  // 64 MB

    _Float16* Wgh = (_Float16*)(w + OFF_WGH);
    _Float16* Wuh = (_Float16*)(w + OFF_WUH);
    _Float16* Wdh = (_Float16*)(w + OFF_WDH);
    _Float16* H   = (_Float16*)(w + OFF_H);
    float*    O   = (float*)(w + OFF_O);

    hipMemsetAsync(w, 0, 1024, stream);  // zero expert counters

    router_kernel<<<T_TOK, 64, 0, stream>>>(x, Wgate, cnt, rows, wts);
    f32to16_kernel<<<(T_TOK * D_DIM / 4) / 256, 256, 0, stream>>>(x, Xh);

    const int WN4 = (NE * F_DIM * D_DIM / 4);
    f32to16_kernel<<<WN4 / 256, 256, 0, stream>>>(Wg, Wgh);
    f32to16_kernel<<<WN4 / 256, 256, 0, stream>>>(Wu, Wuh);
    f32to16_kernel<<<WN4 / 256, 256, 0, stream>>>(Wd, Wdh);

    gateup_kernel<<<dim3(F_DIM / BN2, T_TOK / BM2, NE), 512, 0, stream>>>(
        Xh, Wgh, Wuh, cnt, rows, wts, H);
    down_kernel<<<dim3(D_DIM / 128, T_TOK / BM, NE), 256, 0, stream>>>(
        H, Wdh, cnt, rows, O);
    combine_kernel<<<T_TOK, 256, 0, stream>>>(O, out);
}

// Round 3
// 1183.413 us; speedup vs baseline: 1.0890x; 1.0040x over previous
//
#include <hip/hip_runtime.h>
#include <hip/hip_bf16.h>

#define T_TOK 8192
#define D_DIM 1024
#define F_DIM 4096
#define NE 8

#define BM 128
#define BK 32

// 256x128 gateup geometry
#define BM2 256
#define BN2 128
#define BK2 64
#define KT2 (D_DIM / BK2)

typedef _Float16 v8h __attribute__((ext_vector_type(8)));
typedef float f32x4 __attribute__((ext_vector_type(4)));

__device__ __forceinline__ void async_lds16(void* lds, const void* g) {
    __builtin_amdgcn_global_load_lds(
        (const __attribute__((address_space(1))) void*)g,
        (__attribute__((address_space(3))) void*)lds,
        16, 0, 0);
}

// opaque LDS read with compile-time offset immediate; no alias info -> no compiler drains.
template<int OFF>
__device__ __forceinline__ v8h ds128(unsigned a) {
    v8h r;
    asm volatile("ds_read_b128 %0, %1 offset:%2" : "=v"(r) : "v"(a), "n"(OFF));
    return r;
}

#define LGKM0 asm volatile("s_waitcnt lgkmcnt(0)" ::: "memory")
#define VMCNT0 asm volatile("s_waitcnt vmcnt(0)" ::: "memory")
#define SB0 __builtin_amdgcn_sched_barrier(0)

// ---------------- router: logits -> top2 -> scatter ----------------
__global__ void router_kernel(const float* __restrict__ x,
                              const float* __restrict__ Wgate,
                              int* __restrict__ cnt,
                              int* __restrict__ rows,
                              float* __restrict__ wts) {
    int t = blockIdx.x;
    int lane = threadIdx.x;
    const float* xr = x + (size_t)t * D_DIM;
    float acc[NE];
#pragma unroll
    for (int e = 0; e < NE; ++e) acc[e] = 0.f;
#pragma unroll
    for (int i = 0; i < D_DIM / 64; ++i) {
        int d = i * 64 + lane;
        float xv = xr[d];
#pragma unroll
        for (int e = 0; e < NE; ++e) acc[e] += xv * Wgate[e * D_DIM + d];
    }
#pragma unroll
    for (int off = 32; off > 0; off >>= 1) {
#pragma unroll
        for (int e = 0; e < NE; ++e) acc[e] += __shfl_xor(acc[e], off, 64);
    }
    if (lane == 0) {
        int e0 = 0;
#pragma unroll
        for (int e = 1; e < NE; ++e) if (acc[e] > acc[e0]) e0 = e;
        int e1 = (e0 == 0) ? 1 : 0;
#pragma unroll
        for (int e = 0; e < NE; ++e) if (e != e0 && acc[e] > acc[e1]) e1 = e;
        float w0 = 1.f / (1.f + __expf(acc[e1] - acc[e0]));
        float w1 = 1.f - w0;
        int p0 = atomicAdd(&cnt[e0], 1);
        rows[e0 * T_TOK + p0] = 2 * t;
        wts[e0 * T_TOK + p0] = w0;
        int p1 = atomicAdd(&cnt[e1], 1);
        rows[e1 * T_TOK + p1] = 2 * t + 1;
        wts[e1 * T_TOK + p1] = w1;
    }
}

// ---------------- generic fp32 -> f16 convert (float4 granules) ----------------
__global__ void f32to16_kernel(const float* __restrict__ src, _Float16* __restrict__ dst) {
    int i = blockIdx.x * blockDim.x + threadIdx.x;
    float4 v = ((const float4*)src)[i];
    union { _Float16 h[4]; uint2 u; } pk;
    pk.h[0] = (_Float16)v.x; pk.h[1] = (_Float16)v.y;
    pk.h[2] = (_Float16)v.z; pk.h[3] = (_Float16)v.w;
    *(uint2*)&dst[(size_t)i * 4] = pk.u;
}

// ========== gateup: 256x128 tile, 8 waves, 1-barrier-per-K-tile overlapped pipeline ==========
// r2 post-mortem: 8 barriers/K-tile serialized the LDS-read window (2300 cyc/CU) against the
// MFMA window (2460 cyc/CU) -> 35% util. This version: ONE barrier per K-tile; tile t+1's 8
// global_load_lds issued right after it (full-tile issue->wait distance makes vmcnt(0) free);
// 16 ds_reads issued ahead of the first 32 MFMAs, 8 more ahead of the last 32. LDS pipe and
// matrix pipe overlap within a wave and across freely-slipping waves.
// Hazards: stage(t+1) writes buf(t-1); every wave fully lgkm-drains its reads before its last
// MFMA cluster, hence before tile t's barrier, and stages issue after it. af[] reuse (WAR) is
// pinned after the up-h0 cluster by sched_barrier(0).
__global__ __launch_bounds__(512, 2)
void gateup_kernel(const _Float16* __restrict__ Xh,
                   const _Float16* __restrict__ Wgh,
                   const _Float16* __restrict__ Wuh,
                   const int* __restrict__ cnt,
                   const int* __restrict__ rows,
                   const float* __restrict__ wts,
                   _Float16* __restrict__ H) {
    int e = blockIdx.z;
    int c = cnt[e];
    int row0 = blockIdx.y * BM2;
    if (row0 >= c) return;
    int col0 = blockIdx.x * BN2;

    __shared__ __align__(16) _Float16 Ab[2][BM2][BK2];   // 64 KB
    __shared__ __align__(16) _Float16 Bb[2][BM2][BK2];   // 64 KB
    __shared__ int hrow_s[BM2];
    __shared__ float w_s[BM2];

    int tid = threadIdx.x;
    int lane = tid & 63;
    int wv = tid >> 6;         // 0..7
    int wr = wv >> 2;          // 0..1
    int wc = wv & 3;           // 0..3

    if (tid < BM2) {
        int p = row0 + tid;
        if (p < c) { hrow_s[tid] = rows[e * T_TOK + p]; w_s[tid] = wts[e * T_TOK + p]; }
        else       { hrow_s[tid] = -1;                  w_s[tid] = 0.f; }
    }
    __syncthreads();

    // ---- staging geometry: chunk (wv,l) = 8 rows x 64 cols; lane -> row l8, slot granule g
    int l8 = lane >> 3;            // row within chunk = row&7
    int g  = lane & 7;             // physical 16B granule slot
    int lg = g ^ l8;               // logical granule (involution with row&7)

    int r0 = wv * 16 + l8;         // row-in-half, load0 (chunk wv*2)
    int r1 = r0 + 8;               // load1 (chunk wv*2+1)

    int hA00 = hrow_s[r0],       hA01 = hrow_s[r1];
    int hA10 = hrow_s[128 + r0], hA11 = hrow_s[128 + r1];
    const _Float16* sA00 = Xh + (size_t)(hA00 >= 0 ? (hA00 >> 1) : 0) * D_DIM + lg * 8;
    const _Float16* sA01 = Xh + (size_t)(hA01 >= 0 ? (hA01 >> 1) : 0) * D_DIM + lg * 8;
    const _Float16* sA10 = Xh + (size_t)(hA10 >= 0 ? (hA10 >> 1) : 0) * D_DIM + lg * 8;
    const _Float16* sA11 = Xh + (size_t)(hA11 >= 0 ? (hA11 >> 1) : 0) * D_DIM + lg * 8;
    const _Float16* sB00 = Wgh + ((size_t)e * F_DIM + col0 + r0) * D_DIM + lg * 8;
    const _Float16* sB01 = Wgh + ((size_t)e * F_DIM + col0 + r1) * D_DIM + lg * 8;
    const _Float16* sB10 = Wuh + ((size_t)e * F_DIM + col0 + r0) * D_DIM + lg * 8;
    const _Float16* sB11 = Wuh + ((size_t)e * F_DIM + col0 + r1) * D_DIM + lg * 8;

    int stO0 = wv * 2048 + lane * 16;   // byte offset of (chunk wv*2, lane) within a half

    // ---- fragment-read constants (swizzled)
    int m16 = lane & 15, q4 = lane >> 4;
    int rx = m16 & 7;
    int cb0 = ((q4 ^ rx) << 4);          // kk=0: logical granule q4
    int cb1 = (((4 + q4) ^ rx) << 4);    // kk=1: logical granule 4+q4

    unsigned Abase = (unsigned)(size_t)(__attribute__((address_space(3))) void*)&Ab[0][0][0]
                     + (unsigned)((wr * 16 + m16) * 128);
    unsigned Bbase = (unsigned)(size_t)(__attribute__((address_space(3))) void*)&Bb[0][0][0]
                     + (unsigned)(m16 * 128 + wc * 4096);
    unsigned A0 = Abase + cb0, A1 = Abase + cb1;
    unsigned B0 = Bbase + cb0, B1 = Bbase + cb1;

    // ---- prologue: issue stage of tile 0 into buffer 0 (waited at loop-top vmcnt(0))
    {
        char* a0 = (char*)Ab + stO0;
        char* b0 = (char*)Bb + stO0;
        async_lds16(b0,                sB00);
        async_lds16(b0 + 1024,         sB01);
        async_lds16(a0,                sA00);
        async_lds16(a0 + 1024,         sA01);
        async_lds16(b0 + 16384,        sB10);
        async_lds16(b0 + 16384 + 1024, sB11);
        async_lds16(a0 + 16384,        sA10);
        async_lds16(a0 + 16384 + 1024, sA11);
    }

    f32x4 accg[8][2], accu[8][2];
#pragma unroll
    for (int i = 0; i < 8; ++i)
#pragma unroll
        for (int j = 0; j < 2; ++j) { accg[i][j] = (f32x4)0.f; accu[i][j] = (f32x4)0.f; }

    int cur = 0;
#pragma unroll 1
    for (int t = 0; t < KT2; ++t) {
        int kn = (t + 1 < KT2) ? (t + 1) * BK2 : 0;   // clamped next-tile K offset
        int nb = cur ^ 1;

        // ---- tile boundary: own loads for tile t done; barrier makes all waves' visible
        VMCNT0;
        __builtin_amdgcn_s_barrier();
        SB0;

        // ---- issue stage of tile t+1 into nb (early: full-tile distance to its wait)
        {
            char* aD = (char*)Ab + nb * 32768 + stO0;
            char* bD = (char*)Bb + nb * 32768 + stO0;
            async_lds16(bD,                sB00 + kn);
            async_lds16(bD + 1024,         sB01 + kn);
            async_lds16(aD,                sA00 + kn);
            async_lds16(aD + 1024,         sA01 + kn);
            async_lds16(bD + 16384,        sB10 + kn);
            async_lds16(bD + 16384 + 1024, sB11 + kn);
            async_lds16(aD + 16384,        sA10 + kn);
            async_lds16(aD + 16384 + 1024, sA11 + kn);
        }
        SB0;

        unsigned cOff = (unsigned)(cur * 32768);
        unsigned a0 = A0 + cOff, a1 = A1 + cOff;
        unsigned b0 = B0 + cOff, b1 = B1 + cOff;

        v8h af[4][2], bg[2][2], bu[2][2];

        // ---- reads 1-16: af[0..3] (M-frags 0-3), bg, bu
        af[0][0] = ds128<0>(a0);      af[0][1] = ds128<0>(a1);
        af[1][0] = ds128<4096>(a0);   af[1][1] = ds128<4096>(a1);
        af[2][0] = ds128<8192>(a0);   af[2][1] = ds128<8192>(a1);
        af[3][0] = ds128<12288>(a0);  af[3][1] = ds128<12288>(a1);
        bg[0][0] = ds128<0>(b0);      bg[0][1] = ds128<0>(b1);
        bg[1][0] = ds128<2048>(b0);   bg[1][1] = ds128<2048>(b1);
        bu[0][0] = ds128<16384>(b0);  bu[0][1] = ds128<16384>(b1);
        bu[1][0] = ds128<18432>(b0);  bu[1][1] = ds128<18432>(b1);
        LGKM0;
        SB0;

        // ---- MFMA 1-32: gate-h0, up-h0 (M-frags 0-3)
        __builtin_amdgcn_s_setprio(1);
#pragma unroll
        for (int i = 0; i < 4; ++i)
#pragma unroll
            for (int j = 0; j < 2; ++j) {
                accg[i][j] = __builtin_amdgcn_mfma_f32_16x16x32_f16(af[i][0], bg[j][0], accg[i][j], 0, 0, 0);
                accg[i][j] = __builtin_amdgcn_mfma_f32_16x16x32_f16(af[i][1], bg[j][1], accg[i][j], 0, 0, 0);
            }
#pragma unroll
        for (int i = 0; i < 4; ++i)
#pragma unroll
            for (int j = 0; j < 2; ++j) {
                accu[i][j] = __builtin_amdgcn_mfma_f32_16x16x32_f16(af[i][0], bu[j][0], accu[i][j], 0, 0, 0);
                accu[i][j] = __builtin_amdgcn_mfma_f32_16x16x32_f16(af[i][1], bu[j][1], accu[i][j], 0, 0, 0);
            }
        __builtin_amdgcn_s_setprio(0);
        SB0;   // pin af re-reads below the clusters that consume the old af

        // ---- reads 17-24: af[0..3] <- M-frags 4-7
        af[0][0] = ds128<16384>(a0);  af[0][1] = ds128<16384>(a1);
        af[1][0] = ds128<20480>(a0);  af[1][1] = ds128<20480>(a1);
        af[2][0] = ds128<24576>(a0);  af[2][1] = ds128<24576>(a1);
        af[3][0] = ds128<28672>(a0);  af[3][1] = ds128<28672>(a1);
        LGKM0;
        SB0;

        // ---- MFMA 33-64: gate-h1, up-h1 (M-frags 4-7)
        __builtin_amdgcn_s_setprio(1);
#pragma unroll
        for (int i = 0; i < 4; ++i)
#pragma unroll
            for (int j = 0; j < 2; ++j) {
                accg[i + 4][j] = __builtin_amdgcn_mfma_f32_16x16x32_f16(af[i][0], bg[j][0], accg[i + 4][j], 0, 0, 0);
                accg[i + 4][j] = __builtin_amdgcn_mfma_f32_16x16x32_f16(af[i][1], bg[j][1], accg[i + 4][j], 0, 0, 0);
            }
#pragma unroll
        for (int i = 0; i < 4; ++i)
#pragma unroll
            for (int j = 0; j < 2; ++j) {
                accu[i + 4][j] = __builtin_amdgcn_mfma_f32_16x16x32_f16(af[i][0], bu[j][0], accu[i + 4][j], 0, 0, 0);
                accu[i + 4][j] = __builtin_amdgcn_mfma_f32_16x16x32_f16(af[i][1], bu[j][1], accu[i + 4][j], 0, 0, 0);
            }
        __builtin_amdgcn_s_setprio(0);

        cur = nb;
    }

    // ---------- epilogue: h = silu(g) * w * u -> H (f16) ----------
    int cl = lane & 15;
#pragma unroll
    for (int i = 0; i < 8; ++i) {
#pragma unroll
        for (int j = 0; j < 2; ++j) {
            f32x4 gv = accg[i][j];
            f32x4 uv = accu[i][j];
#pragma unroll
            for (int r4 = 0; r4 < 4; ++r4) {
                int r = i * 32 + wr * 16 + q4 * 4 + r4;
                int hr = hrow_s[r];
                if (hr < 0) continue;
                float gg = gv[r4];
                float h = gg / (1.f + __expf(-gg)) * w_s[r] * uv[r4];
                H[(size_t)hr * F_DIM + col0 + (wc * 2 + j) * 16 + cl] = (_Float16)h;
            }
        }
    }
}

// ---------------- down GEMM: H @ Wd^T -> O (fp32, slot-indexed) ----------------
__global__ __launch_bounds__(256, 2)
void down_kernel(const _Float16* __restrict__ H,
                 const _Float16* __restrict__ Wdh,
                 const int* __restrict__ cnt,
                 const int* __restrict__ rows,
                 float* __restrict__ O) {
    int e = blockIdx.z;
    int c = cnt[e];
    int row0 = blockIdx.y * BM;
    if (row0 >= c) return;
    int col0 = blockIdx.x * 128;

    __shared__ __align__(16) _Float16 As[BM][BK];
    __shared__ __align__(16) _Float16 Bs[128][BK];
    __shared__ int hrow_s[BM];

    int tid = threadIdx.x;
    int lane = tid & 63;
    int wave = tid >> 6;
    int wr = wave >> 1, wc = wave & 1;

    if (tid < BM) {
        int p = row0 + tid;
        hrow_s[tid] = (p < c) ? rows[e * T_TOK + p] : -1;
    }
    __syncthreads();

    int srow = tid >> 2;
    int kch = tid & 3;
    int hr0 = hrow_s[srow], hr1 = hrow_s[srow + 64];
    int r0 = (hr0 >= 0) ? hr0 : 0;
    int r1 = (hr1 >= 0) ? hr1 : 0;

    const _Float16* a0 = H + (size_t)r0 * F_DIM + kch * 8;
    const _Float16* a1 = H + (size_t)r1 * F_DIM + kch * 8;
    const _Float16* b0 = Wdh + ((size_t)e * D_DIM + col0 + srow) * F_DIM + kch * 8;
    const _Float16* b1 = b0 + (size_t)64 * F_DIM;

    _Float16* lA0 = &As[srow][kch * 8];
    _Float16* lA1 = &As[srow + 64][kch * 8];
    _Float16* lB0 = &Bs[srow][kch * 8];
    _Float16* lB1 = &Bs[srow + 64][kch * 8];

    f32x4 acc[4][4];
#pragma unroll
    for (int i = 0; i < 4; ++i)
#pragma unroll
        for (int j = 0; j < 4; ++j) acc[i][j] = (f32x4)0.f;

    int m16 = lane & 15, q8 = (lane >> 4) * 8;

    for (int k0 = 0; k0 < F_DIM; k0 += BK) {
        async_lds16(lA0, a0 + k0);
        async_lds16(lA1, a1 + k0);
        async_lds16(lB0, b0 + k0);
        async_lds16(lB1, b1 + k0);
        __syncthreads();

        v8h af[4], bf[4];
#pragma unroll
        for (int i = 0; i < 4; ++i)
            af[i] = *(const v8h*)&As[wr * 64 + i * 16 + m16][q8];
#pragma unroll
        for (int j = 0; j < 4; ++j)
            bf[j] = *(const v8h*)&Bs[wc * 64 + j * 16 + m16][q8];
#pragma unroll
        for (int i = 0; i < 4; ++i)
#pragma unroll
            for (int j = 0; j < 4; ++j)
                acc[i][j] = __builtin_amdgcn_mfma_f32_16x16x32_f16(af[i], bf[j], acc[i][j], 0, 0, 0);
        __syncthreads();
    }

    int q = lane >> 4, cl = lane & 15;
#pragma unroll
    for (int i = 0; i < 4; ++i) {
#pragma unroll
        for (int r4 = 0; r4 < 4; ++r4) {
            int r = wr * 64 + i * 16 + q * 4 + r4;
            int hr = hrow_s[r];
            if (hr < 0) continue;
#pragma unroll
            for (int j = 0; j < 4; ++j) {
                int col = col0 + wc * 64 + j * 16 + cl;
                O[(size_t)hr * D_DIM + col] = acc[i][j][r4];
            }
        }
    }
}

// ---------------- combine: out[t] = O[2t] + O[2t+1] ----------------
__global__ void combine_kernel(const float* __restrict__ O, float* __restrict__ out) {
    int t = blockIdx.x;
    int d = threadIdx.x;
    const float4* a = (const float4*)(O + (size_t)(2 * t) * D_DIM);
    const float4* b = (const float4*)(O + (size_t)(2 * t + 1) * D_DIM);
    float4 va = a[d], vb = b[d];
    float4 r; r.x = va.x + vb.x; r.y = va.y + vb.y; r.z = va.z + vb.z; r.w = va.w + vb.w;
    ((float4*)(out + (size_t)t * D_DIM))[d] = r;
}

extern "C" void kernel_launch(void* const* d_in, const int* in_sizes, int n_in,
                              void* d_out, int out_size, void* d_ws, size_t ws_size,
                              hipStream_t stream) {
    const float* x     = (const float*)d_in[0];
    const float* Wgate = (const float*)d_in[1];
    const float* Wg    = (const float*)d_in[2];
    const float* Wu    = (const float*)d_in[3];
    const float* Wd    = (const float*)d_in[4];
    float* out = (float*)d_out;

    char* w = (char*)d_ws;
    int*      cnt  = (int*)w;                          // 32 B, zeroed below
    int*      rows = (int*)(w + 1024);                 // 256 KB
    float*    wts  = (float*)(w + 263168);             // 256 KB
    _Float16* Xh   = (_Float16*)(w + 525312);          // 16 MB

    const size_t OFF_WGH = 17302528;                   // 64 MB f16
    const size_t OFF_WUH = 84411392;
    const size_t OFF_WDH = 151520256;
    const size_t OFF_H   = 218629120;                  // 128 MB
    const size_t OFF_O   = 352846848;                  // 64 MB

    _Float16* Wgh = (_Float16*)(w + OFF_WGH);
    _Float16* Wuh = (_Float16*)(w + OFF_WUH);
    _Float16* Wdh = (_Float16*)(w + OFF_WDH);
    _Float16* H   = (_Float16*)(w + OFF_H);
    float*    O   = (float*)(w + OFF_O);

    hipMemsetAsync(w, 0, 1024, stream);  // zero expert counters

    router_kernel<<<T_TOK, 64, 0, stream>>>(x, Wgate, cnt, rows, wts);
    f32to16_kernel<<<(T_TOK * D_DIM / 4) / 256, 256, 0, stream>>>(x, Xh);

    const int WN4 = (NE * F_DIM * D_DIM / 4);
    f32to16_kernel<<<WN4 / 256, 256, 0, stream>>>(Wg, Wgh);
    f32to16_kernel<<<WN4 / 256, 256, 0, stream>>>(Wu, Wuh);
    f32to16_kernel<<<WN4 / 256, 256, 0, stream>>>(Wd, Wdh);

    gateup_kernel<<<dim3(F_DIM / BN2, T_TOK / BM2, NE), 512, 0, stream>>>(
        Xh, Wgh, Wuh, cnt, rows, wts, H);
    down_kernel<<<dim3(D_DIM / 128, T_TOK / BM, NE), 256, 0, stream>>>(
        H, Wdh, cnt, rows, O);
    combine_kernel<<<T_TOK, 256, 0, stream>>>(O, out);
}

// Round 4
// 1180.255 us; speedup vs baseline: 1.0919x; 1.0027x over previous
//
#include <hip/hip_runtime.h>
#include <hip/hip_bf16.h>

#define T_TOK 8192
#define D_DIM 1024
#define F_DIM 4096
#define NE 8

// 256x128 gateup geometry
#define BM2 256
#define BN2 128
#define BK2 64
#define KT2 (D_DIM / BK2)
// down K-tiles
#define KTD (F_DIM / BK2)

typedef _Float16 v8h __attribute__((ext_vector_type(8)));
typedef float f32x4 __attribute__((ext_vector_type(4)));

__device__ __forceinline__ void async_lds16(void* lds, const void* g) {
    __builtin_amdgcn_global_load_lds(
        (const __attribute__((address_space(1))) void*)g,
        (__attribute__((address_space(3))) void*)lds,
        16, 0, 0);
}

// opaque LDS read with compile-time offset immediate; no alias info -> no compiler drains.
template<int OFF>
__device__ __forceinline__ v8h ds128(unsigned a) {
    v8h r;
    asm volatile("ds_read_b128 %0, %1 offset:%2" : "=v"(r) : "v"(a), "n"(OFF));
    return r;
}

#define LGKM0 asm volatile("s_waitcnt lgkmcnt(0)" ::: "memory")
#define VMCNT0 asm volatile("s_waitcnt vmcnt(0)" ::: "memory")
#define SB0 __builtin_amdgcn_sched_barrier(0)

// ---------------- router: logits -> top2 -> scatter ----------------
__global__ void router_kernel(const float* __restrict__ x,
                              const float* __restrict__ Wgate,
                              int* __restrict__ cnt,
                              int* __restrict__ rows,
                              float* __restrict__ wts) {
    int t = blockIdx.x;
    int lane = threadIdx.x;
    const float* xr = x + (size_t)t * D_DIM;
    float acc[NE];
#pragma unroll
    for (int e = 0; e < NE; ++e) acc[e] = 0.f;
#pragma unroll
    for (int i = 0; i < D_DIM / 64; ++i) {
        int d = i * 64 + lane;
        float xv = xr[d];
#pragma unroll
        for (int e = 0; e < NE; ++e) acc[e] += xv * Wgate[e * D_DIM + d];
    }
#pragma unroll
    for (int off = 32; off > 0; off >>= 1) {
#pragma unroll
        for (int e = 0; e < NE; ++e) acc[e] += __shfl_xor(acc[e], off, 64);
    }
    if (lane == 0) {
        int e0 = 0;
#pragma unroll
        for (int e = 1; e < NE; ++e) if (acc[e] > acc[e0]) e0 = e;
        int e1 = (e0 == 0) ? 1 : 0;
#pragma unroll
        for (int e = 0; e < NE; ++e) if (e != e0 && acc[e] > acc[e1]) e1 = e;
        float w0 = 1.f / (1.f + __expf(acc[e1] - acc[e0]));
        float w1 = 1.f - w0;
        int p0 = atomicAdd(&cnt[e0], 1);
        rows[e0 * T_TOK + p0] = 2 * t;
        wts[e0 * T_TOK + p0] = w0;
        int p1 = atomicAdd(&cnt[e1], 1);
        rows[e1 * T_TOK + p1] = 2 * t + 1;
        wts[e1 * T_TOK + p1] = w1;
    }
}

// ---------------- generic fp32 -> f16 convert (float4 granules) ----------------
__global__ void f32to16_kernel(const float* __restrict__ src, _Float16* __restrict__ dst) {
    int i = blockIdx.x * blockDim.x + threadIdx.x;
    float4 v = ((const float4*)src)[i];
    union { _Float16 h[4]; uint2 u; } pk;
    pk.h[0] = (_Float16)v.x; pk.h[1] = (_Float16)v.y;
    pk.h[2] = (_Float16)v.z; pk.h[3] = (_Float16)v.w;
    *(uint2*)&dst[(size_t)i * 4] = pk.u;
}

// ========== gateup: 256x128 tile, 8 waves, 1-barrier-per-K-tile overlapped pipeline ==========
// (frozen from r3 — serves as A/B stability reference this round)
__global__ __launch_bounds__(512, 2)
void gateup_kernel(const _Float16* __restrict__ Xh,
                   const _Float16* __restrict__ Wgh,
                   const _Float16* __restrict__ Wuh,
                   const int* __restrict__ cnt,
                   const int* __restrict__ rows,
                   const float* __restrict__ wts,
                   _Float16* __restrict__ H) {
    int e = blockIdx.z;
    int c = cnt[e];
    int row0 = blockIdx.y * BM2;
    if (row0 >= c) return;
    int col0 = blockIdx.x * BN2;

    __shared__ __align__(16) _Float16 Ab[2][BM2][BK2];   // 64 KB
    __shared__ __align__(16) _Float16 Bb[2][BM2][BK2];   // 64 KB
    __shared__ int hrow_s[BM2];
    __shared__ float w_s[BM2];

    int tid = threadIdx.x;
    int lane = tid & 63;
    int wv = tid >> 6;         // 0..7
    int wr = wv >> 2;          // 0..1
    int wc = wv & 3;           // 0..3

    if (tid < BM2) {
        int p = row0 + tid;
        if (p < c) { hrow_s[tid] = rows[e * T_TOK + p]; w_s[tid] = wts[e * T_TOK + p]; }
        else       { hrow_s[tid] = -1;                  w_s[tid] = 0.f; }
    }
    __syncthreads();

    int l8 = lane >> 3;            // row within chunk = row&7
    int g  = lane & 7;             // physical 16B granule slot
    int lg = g ^ l8;               // logical granule (involution with row&7)

    int r0 = wv * 16 + l8;
    int r1 = r0 + 8;

    int hA00 = hrow_s[r0],       hA01 = hrow_s[r1];
    int hA10 = hrow_s[128 + r0], hA11 = hrow_s[128 + r1];
    const _Float16* sA00 = Xh + (size_t)(hA00 >= 0 ? (hA00 >> 1) : 0) * D_DIM + lg * 8;
    const _Float16* sA01 = Xh + (size_t)(hA01 >= 0 ? (hA01 >> 1) : 0) * D_DIM + lg * 8;
    const _Float16* sA10 = Xh + (size_t)(hA10 >= 0 ? (hA10 >> 1) : 0) * D_DIM + lg * 8;
    const _Float16* sA11 = Xh + (size_t)(hA11 >= 0 ? (hA11 >> 1) : 0) * D_DIM + lg * 8;
    const _Float16* sB00 = Wgh + ((size_t)e * F_DIM + col0 + r0) * D_DIM + lg * 8;
    const _Float16* sB01 = Wgh + ((size_t)e * F_DIM + col0 + r1) * D_DIM + lg * 8;
    const _Float16* sB10 = Wuh + ((size_t)e * F_DIM + col0 + r0) * D_DIM + lg * 8;
    const _Float16* sB11 = Wuh + ((size_t)e * F_DIM + col0 + r1) * D_DIM + lg * 8;

    int stO0 = wv * 2048 + lane * 16;

    int m16 = lane & 15, q4 = lane >> 4;
    int rx = m16 & 7;
    int cb0 = ((q4 ^ rx) << 4);
    int cb1 = (((4 + q4) ^ rx) << 4);

    unsigned Abase = (unsigned)(size_t)(__attribute__((address_space(3))) void*)&Ab[0][0][0]
                     + (unsigned)((wr * 16 + m16) * 128);
    unsigned Bbase = (unsigned)(size_t)(__attribute__((address_space(3))) void*)&Bb[0][0][0]
                     + (unsigned)(m16 * 128 + wc * 4096);
    unsigned A0 = Abase + cb0, A1 = Abase + cb1;
    unsigned B0 = Bbase + cb0, B1 = Bbase + cb1;

    {
        char* a0 = (char*)Ab + stO0;
        char* b0 = (char*)Bb + stO0;
        async_lds16(b0,                sB00);
        async_lds16(b0 + 1024,         sB01);
        async_lds16(a0,                sA00);
        async_lds16(a0 + 1024,         sA01);
        async_lds16(b0 + 16384,        sB10);
        async_lds16(b0 + 16384 + 1024, sB11);
        async_lds16(a0 + 16384,        sA10);
        async_lds16(a0 + 16384 + 1024, sA11);
    }

    f32x4 accg[8][2], accu[8][2];
#pragma unroll
    for (int i = 0; i < 8; ++i)
#pragma unroll
        for (int j = 0; j < 2; ++j) { accg[i][j] = (f32x4)0.f; accu[i][j] = (f32x4)0.f; }

    int cur = 0;
#pragma unroll 1
    for (int t = 0; t < KT2; ++t) {
        int kn = (t + 1 < KT2) ? (t + 1) * BK2 : 0;
        int nb = cur ^ 1;

        VMCNT0;
        __builtin_amdgcn_s_barrier();
        SB0;

        {
            char* aD = (char*)Ab + nb * 32768 + stO0;
            char* bD = (char*)Bb + nb * 32768 + stO0;
            async_lds16(bD,                sB00 + kn);
            async_lds16(bD + 1024,         sB01 + kn);
            async_lds16(aD,                sA00 + kn);
            async_lds16(aD + 1024,         sA01 + kn);
            async_lds16(bD + 16384,        sB10 + kn);
            async_lds16(bD + 16384 + 1024, sB11 + kn);
            async_lds16(aD + 16384,        sA10 + kn);
            async_lds16(aD + 16384 + 1024, sA11 + kn);
        }
        SB0;

        unsigned cOff = (unsigned)(cur * 32768);
        unsigned a0 = A0 + cOff, a1 = A1 + cOff;
        unsigned b0 = B0 + cOff, b1 = B1 + cOff;

        v8h af[4][2], bg[2][2], bu[2][2];

        af[0][0] = ds128<0>(a0);      af[0][1] = ds128<0>(a1);
        af[1][0] = ds128<4096>(a0);   af[1][1] = ds128<4096>(a1);
        af[2][0] = ds128<8192>(a0);   af[2][1] = ds128<8192>(a1);
        af[3][0] = ds128<12288>(a0);  af[3][1] = ds128<12288>(a1);
        bg[0][0] = ds128<0>(b0);      bg[0][1] = ds128<0>(b1);
        bg[1][0] = ds128<2048>(b0);   bg[1][1] = ds128<2048>(b1);
        bu[0][0] = ds128<16384>(b0);  bu[0][1] = ds128<16384>(b1);
        bu[1][0] = ds128<18432>(b0);  bu[1][1] = ds128<18432>(b1);
        LGKM0;
        SB0;

        __builtin_amdgcn_s_setprio(1);
#pragma unroll
        for (int i = 0; i < 4; ++i)
#pragma unroll
            for (int j = 0; j < 2; ++j) {
                accg[i][j] = __builtin_amdgcn_mfma_f32_16x16x32_f16(af[i][0], bg[j][0], accg[i][j], 0, 0, 0);
                accg[i][j] = __builtin_amdgcn_mfma_f32_16x16x32_f16(af[i][1], bg[j][1], accg[i][j], 0, 0, 0);
            }
#pragma unroll
        for (int i = 0; i < 4; ++i)
#pragma unroll
            for (int j = 0; j < 2; ++j) {
                accu[i][j] = __builtin_amdgcn_mfma_f32_16x16x32_f16(af[i][0], bu[j][0], accu[i][j], 0, 0, 0);
                accu[i][j] = __builtin_amdgcn_mfma_f32_16x16x32_f16(af[i][1], bu[j][1], accu[i][j], 0, 0, 0);
            }
        __builtin_amdgcn_s_setprio(0);
        SB0;

        af[0][0] = ds128<16384>(a0);  af[0][1] = ds128<16384>(a1);
        af[1][0] = ds128<20480>(a0);  af[1][1] = ds128<20480>(a1);
        af[2][0] = ds128<24576>(a0);  af[2][1] = ds128<24576>(a1);
        af[3][0] = ds128<28672>(a0);  af[3][1] = ds128<28672>(a1);
        LGKM0;
        SB0;

        __builtin_amdgcn_s_setprio(1);
#pragma unroll
        for (int i = 0; i < 4; ++i)
#pragma unroll
            for (int j = 0; j < 2; ++j) {
                accg[i + 4][j] = __builtin_amdgcn_mfma_f32_16x16x32_f16(af[i][0], bg[j][0], accg[i + 4][j], 0, 0, 0);
                accg[i + 4][j] = __builtin_amdgcn_mfma_f32_16x16x32_f16(af[i][1], bg[j][1], accg[i + 4][j], 0, 0, 0);
            }
#pragma unroll
        for (int i = 0; i < 4; ++i)
#pragma unroll
            for (int j = 0; j < 2; ++j) {
                accu[i + 4][j] = __builtin_amdgcn_mfma_f32_16x16x32_f16(af[i][0], bu[j][0], accu[i + 4][j], 0, 0, 0);
                accu[i + 4][j] = __builtin_amdgcn_mfma_f32_16x16x32_f16(af[i][1], bu[j][1], accu[i + 4][j], 0, 0, 0);
            }
        __builtin_amdgcn_s_setprio(0);

        cur = nb;
    }

    int cl = lane & 15;
#pragma unroll
    for (int i = 0; i < 8; ++i) {
#pragma unroll
        for (int j = 0; j < 2; ++j) {
            f32x4 gv = accg[i][j];
            f32x4 uv = accu[i][j];
#pragma unroll
            for (int r4 = 0; r4 < 4; ++r4) {
                int r = i * 32 + wr * 16 + q4 * 4 + r4;
                int hr = hrow_s[r];
                if (hr < 0) continue;
                float gg = gv[r4];
                float h = gg / (1.f + __expf(-gg)) * w_s[r] * uv[r4];
                H[(size_t)hr * F_DIM + col0 + (wc * 2 + j) * 16 + cl] = (_Float16)h;
            }
        }
    }
}

// ========== down: 256x128 tile, 8 waves (4x2, wave 64x64), BK=64, r3-style pipeline ==========
// Ported from the r3 gateup structure: XOR granule swizzle (bank-conflict-free), opaque
// ds_read_b128, ONE barrier + full-tile-distance vmcnt(0) per K-tile, 64 K-tiles (vs 128
// two-barrier iterations in the old version). A = H slot-rows (gathered), B = Wd cols.
__global__ __launch_bounds__(512, 2)
void down_kernel(const _Float16* __restrict__ H,
                 const _Float16* __restrict__ Wdh,
                 const int* __restrict__ cnt,
                 const int* __restrict__ rows,
                 float* __restrict__ O) {
    int e = blockIdx.z;
    int c = cnt[e];
    int row0 = blockIdx.y * BM2;
    if (row0 >= c) return;
    int col0 = blockIdx.x * 128;

    __shared__ __align__(16) _Float16 Ab[2][BM2][BK2];   // 64 KB
    __shared__ __align__(16) _Float16 Bb[2][128][BK2];   // 32 KB
    __shared__ int hrow_s[BM2];

    int tid = threadIdx.x;
    int lane = tid & 63;
    int wv = tid >> 6;         // 0..7
    int wr = wv >> 1;          // 0..3 (M quadrant, 64 rows each)
    int wc = wv & 1;           // 0..1 (N half, 64 cols each)

    if (tid < BM2) {
        int p = row0 + tid;
        hrow_s[tid] = (p < c) ? rows[e * T_TOK + p] : -1;
    }
    __syncthreads();

    // staging geometry: chunk (wv, lane) = 8 rows x 64 cols; lane -> row l8, granule g
    int l8 = lane >> 3;
    int g  = lane & 7;
    int lg = g ^ l8;               // pre-swizzled logical granule

    int r0 = wv * 16 + l8;         // 0..127
    int r1 = r0 + 8;

    int hA00 = hrow_s[r0],       hA01 = hrow_s[r1];
    int hA10 = hrow_s[128 + r0], hA11 = hrow_s[128 + r1];
    const _Float16* sA00 = H + (size_t)(hA00 >= 0 ? hA00 : 0) * F_DIM + lg * 8;
    const _Float16* sA01 = H + (size_t)(hA01 >= 0 ? hA01 : 0) * F_DIM + lg * 8;
    const _Float16* sA10 = H + (size_t)(hA10 >= 0 ? hA10 : 0) * F_DIM + lg * 8;
    const _Float16* sA11 = H + (size_t)(hA11 >= 0 ? hA11 : 0) * F_DIM + lg * 8;
    const _Float16* sB00 = Wdh + ((size_t)e * D_DIM + col0 + r0) * F_DIM + lg * 8;
    const _Float16* sB01 = Wdh + ((size_t)e * D_DIM + col0 + r1) * F_DIM + lg * 8;

    int stO0 = wv * 2048 + lane * 16;   // byte offset within a 128-row (16 KB) half

    // fragment-read constants (swizzled)
    int m16 = lane & 15, q4 = lane >> 4;
    int rx = m16 & 7;
    int cb0 = ((q4 ^ rx) << 4);
    int cb1 = (((4 + q4) ^ rx) << 4);

    unsigned Abase = (unsigned)(size_t)(__attribute__((address_space(3))) void*)&Ab[0][0][0]
                     + (unsigned)((wr * 64 + m16) * 128);
    unsigned Bbase = (unsigned)(size_t)(__attribute__((address_space(3))) void*)&Bb[0][0][0]
                     + (unsigned)((wc * 64 + m16) * 128);
    unsigned A0 = Abase + cb0, A1 = Abase + cb1;
    unsigned B0 = Bbase + cb0, B1 = Bbase + cb1;

    // prologue: issue stage of tile 0 into buffer 0
    {
        char* a0 = (char*)Ab + stO0;
        char* b0 = (char*)Bb + stO0;
        async_lds16(b0,                sB00);
        async_lds16(b0 + 1024,         sB01);
        async_lds16(a0,                sA00);
        async_lds16(a0 + 1024,         sA01);
        async_lds16(a0 + 16384,        sA10);
        async_lds16(a0 + 16384 + 1024, sA11);
    }

    f32x4 acc[4][4];
#pragma unroll
    for (int i = 0; i < 4; ++i)
#pragma unroll
        for (int j = 0; j < 4; ++j) acc[i][j] = (f32x4)0.f;

    int cur = 0;
#pragma unroll 1
    for (int t = 0; t < KTD; ++t) {
        int kn = (t + 1 < KTD) ? (t + 1) * BK2 : 0;
        int nb = cur ^ 1;

        VMCNT0;
        __builtin_amdgcn_s_barrier();
        SB0;

        {
            char* aD = (char*)Ab + nb * 32768 + stO0;
            char* bD = (char*)Bb + nb * 16384 + stO0;
            async_lds16(bD,                sB00 + kn);
            async_lds16(bD + 1024,         sB01 + kn);
            async_lds16(aD,                sA00 + kn);
            async_lds16(aD + 1024,         sA01 + kn);
            async_lds16(aD + 16384,        sA10 + kn);
            async_lds16(aD + 16384 + 1024, sA11 + kn);
        }
        SB0;

        unsigned a0 = A0 + (unsigned)(cur * 32768);
        unsigned a1 = A1 + (unsigned)(cur * 32768);
        unsigned b0 = B0 + (unsigned)(cur * 16384);
        unsigned b1 = B1 + (unsigned)(cur * 16384);

        v8h af[4][2], bf[4][2];

        af[0][0] = ds128<0>(a0);      af[0][1] = ds128<0>(a1);
        af[1][0] = ds128<2048>(a0);   af[1][1] = ds128<2048>(a1);
        af[2][0] = ds128<4096>(a0);   af[2][1] = ds128<4096>(a1);
        af[3][0] = ds128<6144>(a0);   af[3][1] = ds128<6144>(a1);
        bf[0][0] = ds128<0>(b0);      bf[0][1] = ds128<0>(b1);
        bf[1][0] = ds128<2048>(b0);   bf[1][1] = ds128<2048>(b1);
        bf[2][0] = ds128<4096>(b0);   bf[2][1] = ds128<4096>(b1);
        bf[3][0] = ds128<6144>(b0);   bf[3][1] = ds128<6144>(b1);
        LGKM0;
        SB0;

        __builtin_amdgcn_s_setprio(1);
#pragma unroll
        for (int i = 0; i < 4; ++i)
#pragma unroll
            for (int j = 0; j < 4; ++j) {
                acc[i][j] = __builtin_amdgcn_mfma_f32_16x16x32_f16(af[i][0], bf[j][0], acc[i][j], 0, 0, 0);
                acc[i][j] = __builtin_amdgcn_mfma_f32_16x16x32_f16(af[i][1], bf[j][1], acc[i][j], 0, 0, 0);
            }
        __builtin_amdgcn_s_setprio(0);

        cur = nb;
    }

    int cl = lane & 15;
#pragma unroll
    for (int i = 0; i < 4; ++i) {
#pragma unroll
        for (int r4 = 0; r4 < 4; ++r4) {
            int r = wr * 64 + i * 16 + q4 * 4 + r4;
            int hr = hrow_s[r];
            if (hr < 0) continue;
#pragma unroll
            for (int j = 0; j < 4; ++j) {
                int col = col0 + wc * 64 + j * 16 + cl;
                O[(size_t)hr * D_DIM + col] = acc[i][j][r4];
            }
        }
    }
}

// ---------------- combine: out[t] = O[2t] + O[2t+1] ----------------
__global__ void combine_kernel(const float* __restrict__ O, float* __restrict__ out) {
    int t = blockIdx.x;
    int d = threadIdx.x;
    const float4* a = (const float4*)(O + (size_t)(2 * t) * D_DIM);
    const float4* b = (const float4*)(O + (size_t)(2 * t + 1) * D_DIM);
    float4 va = a[d], vb = b[d];
    float4 r; r.x = va.x + vb.x; r.y = va.y + vb.y; r.z = va.z + vb.z; r.w = va.w + vb.w;
    ((float4*)(out + (size_t)t * D_DIM))[d] = r;
}

extern "C" void kernel_launch(void* const* d_in, const int* in_sizes, int n_in,
                              void* d_out, int out_size, void* d_ws, size_t ws_size,
                              hipStream_t stream) {
    const float* x     = (const float*)d_in[0];
    const float* Wgate = (const float*)d_in[1];
    const float* Wg    = (const float*)d_in[2];
    const float* Wu    = (const float*)d_in[3];
    const float* Wd    = (const float*)d_in[4];
    float* out = (float*)d_out;

    char* w = (char*)d_ws;
    int*      cnt  = (int*)w;                          // 32 B, zeroed below
    int*      rows = (int*)(w + 1024);                 // 256 KB
    float*    wts  = (float*)(w + 263168);             // 256 KB
    _Float16* Xh   = (_Float16*)(w + 525312);          // 16 MB

    const size_t OFF_WGH = 17302528;                   // 64 MB f16
    const size_t OFF_WUH = 84411392;
    const size_t OFF_WDH = 151520256;
    const size_t OFF_H   = 218629120;                  // 128 MB
    const size_t OFF_O   = 352846848;                  // 64 MB

    _Float16* Wgh = (_Float16*)(w + OFF_WGH);
    _Float16* Wuh = (_Float16*)(w + OFF_WUH);
    _Float16* Wdh = (_Float16*)(w + OFF_WDH);
    _Float16* H   = (_Float16*)(w + OFF_H);
    float*    O   = (float*)(w + OFF_O);

    hipMemsetAsync(w, 0, 1024, stream);  // zero expert counters

    router_kernel<<<T_TOK, 64, 0, stream>>>(x, Wgate, cnt, rows, wts);
    f32to16_kernel<<<(T_TOK * D_DIM / 4) / 256, 256, 0, stream>>>(x, Xh);

    const int WN4 = (NE * F_DIM * D_DIM / 4);
    f32to16_kernel<<<WN4 / 256, 256, 0, stream>>>(Wg, Wgh);
    f32to16_kernel<<<WN4 / 256, 256, 0, stream>>>(Wu, Wuh);
    f32to16_kernel<<<WN4 / 256, 256, 0, stream>>>(Wd, Wdh);

    gateup_kernel<<<dim3(F_DIM / BN2, T_TOK / BM2, NE), 512, 0, stream>>>(
        Xh, Wgh, Wuh, cnt, rows, wts, H);
    down_kernel<<<dim3(D_DIM / 128, T_TOK / BM2, NE), 512, 0, stream>>>(
        H, Wdh, cnt, rows, O);
    combine_kernel<<<T_TOK, 256, 0, stream>>>(O, out);
}